// Round 7
// baseline (396.776 us; speedup 1.0000x reference)
//
#include <hip/hip_runtime.h>
#include <math.h>

#define B_   32
#define S_   4
#define H_   16
#define D_   64
#define E_   1024
#define KV_  4096
#define NBH  512            // B_*H_
#define CS   512            // cached rows per chunk
#define NC   9              // 8 cache chunks + 1 "new rows" chunk
#define RECSZ 264           // 4 m + 4 l + 256 O floats per partial record

// ---------------------------------------------------------------------------
// R2-verified GEMM block: A[4][1024] (LDS) x W rows [n0..n0+63] -> res[256].
// g-loop structure exactly as measured in the 244.8us run.
// ---------------------------------------------------------------------------
__device__ __forceinline__ void gemm_block(const float* __restrict__ a_lds,
                                           const float* __restrict__ W,
                                           int n0, int tid,
                                           float* __restrict__ res) {
    const int lane = tid & 63, wid = tid >> 6;
    const int sub = lane >> 4, cg = lane & 15, tsel = cg & 3;
    #pragma unroll
    for (int g = 0; g < 4; ++g) {
        const int r0 = n0 + wid * 16 + g * 4;       // 4 W-rows for this wave
        const float4* wrow = (const float4*)(W + (size_t)r0 * E_);
        float ac0 = 0.f, ac1 = 0.f, ac2 = 0.f, ac3 = 0.f;
        #pragma unroll
        for (int kk = 0; kk < 16; ++kk) {
            float4 w4 = wrow[sub * 256 + kk * 16 + cg];
            float4 a0 = *(const float4*)&a_lds[0 * E_ + kk * 64 + cg * 4];
            float4 a1 = *(const float4*)&a_lds[1 * E_ + kk * 64 + cg * 4];
            float4 a2 = *(const float4*)&a_lds[2 * E_ + kk * 64 + cg * 4];
            float4 a3 = *(const float4*)&a_lds[3 * E_ + kk * 64 + cg * 4];
            ac0 += w4.x * a0.x + w4.y * a0.y + w4.z * a0.z + w4.w * a0.w;
            ac1 += w4.x * a1.x + w4.y * a1.y + w4.z * a1.z + w4.w * a1.w;
            ac2 += w4.x * a2.x + w4.y * a2.y + w4.z * a2.z + w4.w * a2.w;
            ac3 += w4.x * a3.x + w4.y * a3.y + w4.z * a3.z + w4.w * a3.w;
        }
        ac0 += __shfl_xor(ac0, 1); ac0 += __shfl_xor(ac0, 2);
        ac1 += __shfl_xor(ac1, 1); ac1 += __shfl_xor(ac1, 2);
        ac2 += __shfl_xor(ac2, 1); ac2 += __shfl_xor(ac2, 2);
        ac3 += __shfl_xor(ac3, 1); ac3 += __shfl_xor(ac3, 2);
        float v = (tsel & 1) ? ((tsel & 2) ? ac3 : ac1)
                             : ((tsel & 2) ? ac2 : ac0);
        v += __shfl_xor(v, 4); v += __shfl_xor(v, 8);
        if (cg < 4) res[cg * 64 + (wid * 16 + g * 4 + sub)] = v;
    }
}

// ---------------------------------------------------------------------------
// Q/K/V projection (R2-exact). grid (32,16), block 256.
// out = x @ W.T + b, scattered to [b,h,s,d]
// ---------------------------------------------------------------------------
__global__ __launch_bounds__(256) void proj_kernel(
    const float* __restrict__ A, const float* __restrict__ W,
    const float* __restrict__ bias, float* __restrict__ out) {
    __shared__ float a_lds[4 * E_];
    __shared__ float res[256];
    const int t0 = blockIdx.x * 4;
    const int n0 = blockIdx.y * 64;
    const int tid = threadIdx.x;

    const float4* Ag = (const float4*)(A + (size_t)t0 * E_);
    float4* al = (float4*)a_lds;
    #pragma unroll
    for (int i = 0; i < 4; ++i) al[tid + 256 * i] = Ag[tid + 256 * i];
    __syncthreads();

    gemm_block(a_lds, W, n0, tid, res);
    __syncthreads();

    const float val = res[tid] + bias[n0 + (tid & 63)];
    const int t = t0 + (tid >> 6), e = n0 + (tid & 63);
    const int b = t >> 2, s = t & 3, h = e >> 6, dk = e & 63;
    out[((size_t)((b * H_ + h) * S_ + s)) * D_ + dk] = val;
}

// ---------------------------------------------------------------------------
// Attention partials (R2-exact 3-phase, fully coalesced 1KB wave loads)
// ---------------------------------------------------------------------------
__device__ __forceinline__ float wave_sum(float v) {
    #pragma unroll
    for (int off = 32; off > 0; off >>= 1) v += __shfl_xor(v, off);
    return v;
}

__global__ __launch_bounds__(256) void attn_partial_kernel(
    const float* __restrict__ Qw, const float* __restrict__ Kc,
    const float* __restrict__ Vc, const float* __restrict__ Kn,
    const float* __restrict__ Vn, float* __restrict__ part) {
    __shared__ float q_s[S_ * D_];
    __shared__ float ps[CS][4];
    __shared__ float ob[4][256];
    __shared__ float wred[4][4];
    __shared__ float msh[4], lsh[4];

    const int bh = blockIdx.x;
    const int c = blockIdx.y;
    const int tid = threadIdx.x;
    const int lane = tid & 63, wid = tid >> 6;
    const int sub = lane >> 4, cg = lane & 15, qsel = cg & 3;

    q_s[tid] = Qw[(size_t)bh * 256 + tid];
    __syncthreads();

    const float* kptr;
    const float* vptr;
    int nrows;
    if (c < 8) {
        kptr = Kc + ((size_t)bh * KV_ + c * CS) * D_;
        vptr = Vc + ((size_t)bh * KV_ + c * CS) * D_;
        nrows = CS;
    } else {
        kptr = Kn + (size_t)bh * 256;
        vptr = Vn + (size_t)bh * 256;
        nrows = S_;
    }

    // per-lane Q fragments: query q, dims cg*4 .. cg*4+3
    const float4 q0 = *(const float4*)&q_s[0 * 64 + cg * 4];
    const float4 q1 = *(const float4*)&q_s[1 * 64 + cg * 4];
    const float4 q2 = *(const float4*)&q_s[2 * 64 + cg * 4];
    const float4 q3 = *(const float4*)&q_s[3 * 64 + cg * 4];

    // ---- score phase: wave load = 4 consecutive K rows (1KB contiguous) ----
    float mrun = -1e30f;
    for (int r0 = wid * 4; r0 < nrows; r0 += 16) {
        float4 kv = ((const float4*)(kptr + (size_t)r0 * D_))[lane];
        float p0 = kv.x * q0.x + kv.y * q0.y + kv.z * q0.z + kv.w * q0.w;
        float p1 = kv.x * q1.x + kv.y * q1.y + kv.z * q1.z + kv.w * q1.w;
        float p2 = kv.x * q2.x + kv.y * q2.y + kv.z * q2.z + kv.w * q2.w;
        float p3 = kv.x * q3.x + kv.y * q3.y + kv.z * q3.z + kv.w * q3.w;
        p0 += __shfl_xor(p0, 1); p0 += __shfl_xor(p0, 2);
        p1 += __shfl_xor(p1, 1); p1 += __shfl_xor(p1, 2);
        p2 += __shfl_xor(p2, 1); p2 += __shfl_xor(p2, 2);
        p3 += __shfl_xor(p3, 1); p3 += __shfl_xor(p3, 2);
        float v = (qsel & 1) ? ((qsel & 2) ? p3 : p1)
                             : ((qsel & 2) ? p2 : p0);
        v += __shfl_xor(v, 4); v += __shfl_xor(v, 8);
        v *= 0.125f;                                 // 1/sqrt(64)
        mrun = fmaxf(mrun, v);
        if (cg < 4) ps[r0 + sub][cg] = v;
    }
    mrun = fmaxf(mrun, __shfl_xor(mrun, 16));
    mrun = fmaxf(mrun, __shfl_xor(mrun, 32));
    if (lane < 4) wred[lane][wid] = mrun;
    __syncthreads();
    if (tid < 4) {
        msh[tid] = fmaxf(fmaxf(wred[tid][0], wred[tid][1]),
                         fmaxf(wred[tid][2], wred[tid][3]));
    }
    __syncthreads();
    const float m0 = msh[0], m1 = msh[1], m2 = msh[2], m3 = msh[3];

    // ---- exp pass: ps -> exp(ps - m), accumulate l ----
    float4 tl = make_float4(0.f, 0.f, 0.f, 0.f);
    for (int r = tid; r < nrows; r += 256) {
        float4 s = *(float4*)ps[r];
        s.x = __expf(s.x - m0); s.y = __expf(s.y - m1);
        s.z = __expf(s.z - m2); s.w = __expf(s.w - m3);
        *(float4*)ps[r] = s;
        tl.x += s.x; tl.y += s.y; tl.z += s.z; tl.w += s.w;
    }
    tl.x = wave_sum(tl.x); tl.y = wave_sum(tl.y);
    tl.z = wave_sum(tl.z); tl.w = wave_sum(tl.w);
    if (lane == 0) {
        wred[0][wid] = tl.x; wred[1][wid] = tl.y;
        wred[2][wid] = tl.z; wred[3][wid] = tl.w;
    }
    __syncthreads();
    if (tid < 4) {
        lsh[tid] = wred[tid][0] + wred[tid][1] + wred[tid][2] + wred[tid][3];
    }
    __syncthreads();   // ps[] fully exp'd and visible

    // ---- phase B: wave load = 4 consecutive V rows (1KB contiguous) ----
    float4 a0 = make_float4(0.f, 0.f, 0.f, 0.f);
    float4 a1 = a0, a2 = a0, a3 = a0;
    for (int r0 = wid * 4; r0 < nrows; r0 += 16) {
        float4 vv = ((const float4*)(vptr + (size_t)r0 * D_))[lane];
        float4 p = *(const float4*)ps[r0 + sub];
        a0.x = fmaf(p.x, vv.x, a0.x); a0.y = fmaf(p.x, vv.y, a0.y);
        a0.z = fmaf(p.x, vv.z, a0.z); a0.w = fmaf(p.x, vv.w, a0.w);
        a1.x = fmaf(p.y, vv.x, a1.x); a1.y = fmaf(p.y, vv.y, a1.y);
        a1.z = fmaf(p.y, vv.z, a1.z); a1.w = fmaf(p.y, vv.w, a1.w);
        a2.x = fmaf(p.z, vv.x, a2.x); a2.y = fmaf(p.z, vv.y, a2.y);
        a2.z = fmaf(p.z, vv.z, a2.z); a2.w = fmaf(p.z, vv.w, a2.w);
        a3.x = fmaf(p.w, vv.x, a3.x); a3.y = fmaf(p.w, vv.y, a3.y);
        a3.z = fmaf(p.w, vv.z, a3.z); a3.w = fmaf(p.w, vv.w, a3.w);
    }
    a0.x += __shfl_xor(a0.x, 16); a0.x += __shfl_xor(a0.x, 32);
    a0.y += __shfl_xor(a0.y, 16); a0.y += __shfl_xor(a0.y, 32);
    a0.z += __shfl_xor(a0.z, 16); a0.z += __shfl_xor(a0.z, 32);
    a0.w += __shfl_xor(a0.w, 16); a0.w += __shfl_xor(a0.w, 32);
    a1.x += __shfl_xor(a1.x, 16); a1.x += __shfl_xor(a1.x, 32);
    a1.y += __shfl_xor(a1.y, 16); a1.y += __shfl_xor(a1.y, 32);
    a1.z += __shfl_xor(a1.z, 16); a1.z += __shfl_xor(a1.z, 32);
    a1.w += __shfl_xor(a1.w, 16); a1.w += __shfl_xor(a1.w, 32);
    a2.x += __shfl_xor(a2.x, 16); a2.x += __shfl_xor(a2.x, 32);
    a2.y += __shfl_xor(a2.y, 16); a2.y += __shfl_xor(a2.y, 32);
    a2.z += __shfl_xor(a2.z, 16); a2.z += __shfl_xor(a2.z, 32);
    a2.w += __shfl_xor(a2.w, 16); a2.w += __shfl_xor(a2.w, 32);
    a3.x += __shfl_xor(a3.x, 16); a3.x += __shfl_xor(a3.x, 32);
    a3.y += __shfl_xor(a3.y, 16); a3.y += __shfl_xor(a3.y, 32);
    a3.z += __shfl_xor(a3.z, 16); a3.z += __shfl_xor(a3.z, 32);
    a3.w += __shfl_xor(a3.w, 16); a3.w += __shfl_xor(a3.w, 32);
    if (sub == 0) {
        *(float4*)&ob[wid][0 * 64 + cg * 4] = a0;
        *(float4*)&ob[wid][1 * 64 + cg * 4] = a1;
        *(float4*)&ob[wid][2 * 64 + cg * 4] = a2;
        *(float4*)&ob[wid][3 * 64 + cg * 4] = a3;
    }
    __syncthreads();

    float* rec = part + ((size_t)bh * NC + c) * RECSZ;
    if (tid < 4) {
        rec[tid] = msh[tid];
        rec[4 + tid] = lsh[tid];
    }
    rec[8 + tid] = ob[0][tid] + ob[1][tid] + ob[2][tid] + ob[3][tid];
}

// ---------------------------------------------------------------------------
// Fused combine + output projection. grid (32, 16), block 256.
// Block (b, n0): rebuild batch b's combined attention activation from `part`
// (L2-resident) into LDS, then run the R2-verified GEMM against Wo.
// ---------------------------------------------------------------------------
__global__ __launch_bounds__(256) void combine_proj_out_kernel(
    const float* __restrict__ part, const float* __restrict__ Wo,
    const float* __restrict__ bo, float* __restrict__ out) {
    __shared__ float a_lds[4 * E_];
    __shared__ float res[256];
    __shared__ float wcoef[64][NC + 1];    // [h*4+s][c], padded
    __shared__ float linv[64];
    const int b = blockIdx.x;
    const int n0 = blockIdx.y * 64;
    const int tid = threadIdx.x;

    // phase 1a: per-(h,s) combine weights
    if (tid < 64) {
        const int h = tid >> 2, s = tid & 3;
        const float* base = part + ((size_t)(b * H_ + h) * NC) * RECSZ;
        float m = -1e30f;
        #pragma unroll
        for (int c = 0; c < NC; ++c) m = fmaxf(m, base[c * RECSZ + s]);
        float l = 0.f;
        #pragma unroll
        for (int c = 0; c < NC; ++c) {
            const float w = __expf(base[c * RECSZ + s] - m);
            wcoef[tid][c] = w;
            l = fmaf(base[c * RECSZ + 4 + s], w, l);
        }
        linv[tid] = 1.f / l;
    }
    __syncthreads();

    // phase 1b: a_lds[s][h*64+dk] = sum_c w_c * O_c(s,h,dk) / l
    float4* al4 = (float4*)a_lds;
    #pragma unroll
    for (int i = 0; i < 4; ++i) {
        const int idx = tid + 256 * i;     // float4 slot: s*256 + h*16 + dkg
        const int s = idx >> 8;
        const int rest = idx & 255;
        const int h = rest >> 4, dkg = rest & 15;
        const float* base = part + ((size_t)(b * H_ + h) * NC) * RECSZ
                          + 8 + s * 64 + dkg * 4;
        float4 o = make_float4(0.f, 0.f, 0.f, 0.f);
        #pragma unroll
        for (int c = 0; c < NC; ++c) {
            const float4 v = *(const float4*)(base + c * RECSZ);
            const float w = wcoef[h * 4 + s][c];
            o.x = fmaf(w, v.x, o.x); o.y = fmaf(w, v.y, o.y);
            o.z = fmaf(w, v.z, o.z); o.w = fmaf(w, v.w, o.w);
        }
        const float li = linv[h * 4 + s];
        o.x *= li; o.y *= li; o.z *= li; o.w *= li;
        al4[idx] = o;
    }
    __syncthreads();

    gemm_block(a_lds, Wo, n0, tid, res);
    __syncthreads();

    out[(size_t)(b * 4 + (tid >> 6)) * E_ + n0 + (tid & 63)] =
        res[tid] + bo[n0 + (tid & 63)];
}

// ---------------------------------------------------------------------------
extern "C" void kernel_launch(void* const* d_in, const int* in_sizes, int n_in,
                              void* d_out, int out_size, void* d_ws, size_t ws_size,
                              hipStream_t stream) {
    const float* x  = (const float*)d_in[0];
    const float* ck = (const float*)d_in[1];
    const float* cv = (const float*)d_in[2];
    const float* Wq = (const float*)d_in[3];
    const float* bq = (const float*)d_in[4];
    const float* Wk = (const float*)d_in[5];
    const float* bk = (const float*)d_in[6];
    const float* Wv = (const float*)d_in[7];
    const float* bv = (const float*)d_in[8];
    const float* Wo = (const float*)d_in[9];
    const float* bo = (const float*)d_in[10];
    float* out = (float*)d_out;
    float* ws = (float*)d_ws;

    float* Qw = ws;                           // 131072 floats
    float* Kn = ws + 131072;                  // 131072
    float* Vn = ws + 262144;                  // 131072
    float* part = ws + 393216;                // 512*9*264 = 1216512

    dim3 pg(32, 16), pb(256);
    hipLaunchKernelGGL(proj_kernel, pg, pb, 0, stream, x, Wq, bq, Qw);
    hipLaunchKernelGGL(proj_kernel, pg, pb, 0, stream, x, Wk, bk, Kn);
    hipLaunchKernelGGL(proj_kernel, pg, pb, 0, stream, x, Wv, bv, Vn);
    hipLaunchKernelGGL(attn_partial_kernel, dim3(NBH, NC), dim3(256), 0, stream,
                       Qw, ck, cv, Kn, Vn, part);
    hipLaunchKernelGGL(combine_proj_out_kernel, dim3(32, 16), dim3(256), 0, stream,
                       part, Wo, bo, out);
}

// Round 8
// 393.015 us; speedup vs baseline: 1.0096x; 1.0096x over previous
//
#include <hip/hip_runtime.h>
#include <math.h>

#define B_   32
#define S_   4
#define H_   16
#define D_   64
#define E_   1024
#define KV_  4096
#define NBH  512            // B_*H_
#define CS   512            // cached rows per chunk
#define NC   9              // 8 cache chunks + 1 "new rows" chunk
#define RECSZ 264           // 4 m + 4 l + 256 O floats per partial record

// ---------------------------------------------------------------------------
// R2-verified GEMM block: A[4][1024] (LDS) x W rows [n0..n0+63] -> res[256].
// g-loop structure exactly as measured in the 244.8us run.
// ---------------------------------------------------------------------------
__device__ __forceinline__ void gemm_block(const float* __restrict__ a_lds,
                                           const float* __restrict__ W,
                                           int n0, int tid,
                                           float* __restrict__ res) {
    const int lane = tid & 63, wid = tid >> 6;
    const int sub = lane >> 4, cg = lane & 15, tsel = cg & 3;
    #pragma unroll
    for (int g = 0; g < 4; ++g) {
        const int r0 = n0 + wid * 16 + g * 4;       // 4 W-rows for this wave
        const float4* wrow = (const float4*)(W + (size_t)r0 * E_);
        float ac0 = 0.f, ac1 = 0.f, ac2 = 0.f, ac3 = 0.f;
        #pragma unroll
        for (int kk = 0; kk < 16; ++kk) {
            float4 w4 = wrow[sub * 256 + kk * 16 + cg];
            float4 a0 = *(const float4*)&a_lds[0 * E_ + kk * 64 + cg * 4];
            float4 a1 = *(const float4*)&a_lds[1 * E_ + kk * 64 + cg * 4];
            float4 a2 = *(const float4*)&a_lds[2 * E_ + kk * 64 + cg * 4];
            float4 a3 = *(const float4*)&a_lds[3 * E_ + kk * 64 + cg * 4];
            ac0 += w4.x * a0.x + w4.y * a0.y + w4.z * a0.z + w4.w * a0.w;
            ac1 += w4.x * a1.x + w4.y * a1.y + w4.z * a1.z + w4.w * a1.w;
            ac2 += w4.x * a2.x + w4.y * a2.y + w4.z * a2.z + w4.w * a2.w;
            ac3 += w4.x * a3.x + w4.y * a3.y + w4.z * a3.z + w4.w * a3.w;
        }
        ac0 += __shfl_xor(ac0, 1); ac0 += __shfl_xor(ac0, 2);
        ac1 += __shfl_xor(ac1, 1); ac1 += __shfl_xor(ac1, 2);
        ac2 += __shfl_xor(ac2, 1); ac2 += __shfl_xor(ac2, 2);
        ac3 += __shfl_xor(ac3, 1); ac3 += __shfl_xor(ac3, 2);
        float v = (tsel & 1) ? ((tsel & 2) ? ac3 : ac1)
                             : ((tsel & 2) ? ac2 : ac0);
        v += __shfl_xor(v, 4); v += __shfl_xor(v, 8);
        if (cg < 4) res[cg * 64 + (wid * 16 + g * 4 + sub)] = v;
    }
}

// ---------------------------------------------------------------------------
// Fused Q/K/V projection. grid (32, 16, 3), block 256.
// z selects {Wq,Wk,Wv}; output scattered to [b,h,s,d] at outbase + z*131072.
// R2 GEMM core; z-fusion removes two launch gaps.
// ---------------------------------------------------------------------------
__global__ __launch_bounds__(256) void proj_qkv_kernel(
    const float* __restrict__ x,
    const float* __restrict__ Wq, const float* __restrict__ bq,
    const float* __restrict__ Wk, const float* __restrict__ bk,
    const float* __restrict__ Wv, const float* __restrict__ bv,
    float* __restrict__ outbase) {
    __shared__ float a_lds[4 * E_];
    __shared__ float res[256];
    const int t0 = blockIdx.x * 4;
    const int n0 = blockIdx.y * 64;
    const int z = blockIdx.z;
    const int tid = threadIdx.x;

    const float* W    = (z == 0) ? Wq : (z == 1) ? Wk : Wv;
    const float* bias = (z == 0) ? bq : (z == 1) ? bk : bv;
    float* out = outbase + (size_t)z * (B_ * S_ * E_);

    const float4* Ag = (const float4*)(x + (size_t)t0 * E_);
    float4* al = (float4*)a_lds;
    #pragma unroll
    for (int i = 0; i < 4; ++i) al[tid + 256 * i] = Ag[tid + 256 * i];
    __syncthreads();

    gemm_block(a_lds, W, n0, tid, res);
    __syncthreads();

    const float val = res[tid] + bias[n0 + (tid & 63)];
    const int t = t0 + (tid >> 6), e = n0 + (tid & 63);
    const int b = t >> 2, s = t & 3, h = e >> 6, dk = e & 63;
    out[((size_t)((b * H_ + h) * S_ + s)) * D_ + dk] = val;
}

// ---------------------------------------------------------------------------
// Attention partials (R2-exact 3-phase, fully coalesced 1KB wave loads)
// ---------------------------------------------------------------------------
__device__ __forceinline__ float wave_sum(float v) {
    #pragma unroll
    for (int off = 32; off > 0; off >>= 1) v += __shfl_xor(v, off);
    return v;
}

__global__ __launch_bounds__(256) void attn_partial_kernel(
    const float* __restrict__ Qw, const float* __restrict__ Kc,
    const float* __restrict__ Vc, const float* __restrict__ Kn,
    const float* __restrict__ Vn, float* __restrict__ part) {
    __shared__ float q_s[S_ * D_];
    __shared__ float ps[CS][4];
    __shared__ float ob[4][256];
    __shared__ float wred[4][4];
    __shared__ float msh[4], lsh[4];

    const int bh = blockIdx.x;
    const int c = blockIdx.y;
    const int tid = threadIdx.x;
    const int lane = tid & 63, wid = tid >> 6;
    const int sub = lane >> 4, cg = lane & 15, qsel = cg & 3;

    q_s[tid] = Qw[(size_t)bh * 256 + tid];
    __syncthreads();

    const float* kptr;
    const float* vptr;
    int nrows;
    if (c < 8) {
        kptr = Kc + ((size_t)bh * KV_ + c * CS) * D_;
        vptr = Vc + ((size_t)bh * KV_ + c * CS) * D_;
        nrows = CS;
    } else {
        kptr = Kn + (size_t)bh * 256;
        vptr = Vn + (size_t)bh * 256;
        nrows = S_;
    }

    // per-lane Q fragments: query q, dims cg*4 .. cg*4+3
    const float4 q0 = *(const float4*)&q_s[0 * 64 + cg * 4];
    const float4 q1 = *(const float4*)&q_s[1 * 64 + cg * 4];
    const float4 q2 = *(const float4*)&q_s[2 * 64 + cg * 4];
    const float4 q3 = *(const float4*)&q_s[3 * 64 + cg * 4];

    // ---- score phase: wave load = 4 consecutive K rows (1KB contiguous) ----
    float mrun = -1e30f;
    for (int r0 = wid * 4; r0 < nrows; r0 += 16) {
        float4 kv = ((const float4*)(kptr + (size_t)r0 * D_))[lane];
        float p0 = kv.x * q0.x + kv.y * q0.y + kv.z * q0.z + kv.w * q0.w;
        float p1 = kv.x * q1.x + kv.y * q1.y + kv.z * q1.z + kv.w * q1.w;
        float p2 = kv.x * q2.x + kv.y * q2.y + kv.z * q2.z + kv.w * q2.w;
        float p3 = kv.x * q3.x + kv.y * q3.y + kv.z * q3.z + kv.w * q3.w;
        p0 += __shfl_xor(p0, 1); p0 += __shfl_xor(p0, 2);
        p1 += __shfl_xor(p1, 1); p1 += __shfl_xor(p1, 2);
        p2 += __shfl_xor(p2, 1); p2 += __shfl_xor(p2, 2);
        p3 += __shfl_xor(p3, 1); p3 += __shfl_xor(p3, 2);
        float v = (qsel & 1) ? ((qsel & 2) ? p3 : p1)
                             : ((qsel & 2) ? p2 : p0);
        v += __shfl_xor(v, 4); v += __shfl_xor(v, 8);
        v *= 0.125f;                                 // 1/sqrt(64)
        mrun = fmaxf(mrun, v);
        if (cg < 4) ps[r0 + sub][cg] = v;
    }
    mrun = fmaxf(mrun, __shfl_xor(mrun, 16));
    mrun = fmaxf(mrun, __shfl_xor(mrun, 32));
    if (lane < 4) wred[lane][wid] = mrun;
    __syncthreads();
    if (tid < 4) {
        msh[tid] = fmaxf(fmaxf(wred[tid][0], wred[tid][1]),
                         fmaxf(wred[tid][2], wred[tid][3]));
    }
    __syncthreads();
    const float m0 = msh[0], m1 = msh[1], m2 = msh[2], m3 = msh[3];

    // ---- exp pass: ps -> exp(ps - m), accumulate l ----
    float4 tl = make_float4(0.f, 0.f, 0.f, 0.f);
    for (int r = tid; r < nrows; r += 256) {
        float4 s = *(float4*)ps[r];
        s.x = __expf(s.x - m0); s.y = __expf(s.y - m1);
        s.z = __expf(s.z - m2); s.w = __expf(s.w - m3);
        *(float4*)ps[r] = s;
        tl.x += s.x; tl.y += s.y; tl.z += s.z; tl.w += s.w;
    }
    tl.x = wave_sum(tl.x); tl.y = wave_sum(tl.y);
    tl.z = wave_sum(tl.z); tl.w = wave_sum(tl.w);
    if (lane == 0) {
        wred[0][wid] = tl.x; wred[1][wid] = tl.y;
        wred[2][wid] = tl.z; wred[3][wid] = tl.w;
    }
    __syncthreads();
    if (tid < 4) {
        lsh[tid] = wred[tid][0] + wred[tid][1] + wred[tid][2] + wred[tid][3];
    }
    __syncthreads();   // ps[] fully exp'd and visible

    // ---- phase B: wave load = 4 consecutive V rows (1KB contiguous) ----
    float4 a0 = make_float4(0.f, 0.f, 0.f, 0.f);
    float4 a1 = a0, a2 = a0, a3 = a0;
    for (int r0 = wid * 4; r0 < nrows; r0 += 16) {
        float4 vv = ((const float4*)(vptr + (size_t)r0 * D_))[lane];
        float4 p = *(const float4*)ps[r0 + sub];
        a0.x = fmaf(p.x, vv.x, a0.x); a0.y = fmaf(p.x, vv.y, a0.y);
        a0.z = fmaf(p.x, vv.z, a0.z); a0.w = fmaf(p.x, vv.w, a0.w);
        a1.x = fmaf(p.y, vv.x, a1.x); a1.y = fmaf(p.y, vv.y, a1.y);
        a1.z = fmaf(p.y, vv.z, a1.z); a1.w = fmaf(p.y, vv.w, a1.w);
        a2.x = fmaf(p.z, vv.x, a2.x); a2.y = fmaf(p.z, vv.y, a2.y);
        a2.z = fmaf(p.z, vv.z, a2.z); a2.w = fmaf(p.z, vv.w, a2.w);
        a3.x = fmaf(p.w, vv.x, a3.x); a3.y = fmaf(p.w, vv.y, a3.y);
        a3.z = fmaf(p.w, vv.z, a3.z); a3.w = fmaf(p.w, vv.w, a3.w);
    }
    a0.x += __shfl_xor(a0.x, 16); a0.x += __shfl_xor(a0.x, 32);
    a0.y += __shfl_xor(a0.y, 16); a0.y += __shfl_xor(a0.y, 32);
    a0.z += __shfl_xor(a0.z, 16); a0.z += __shfl_xor(a0.z, 32);
    a0.w += __shfl_xor(a0.w, 16); a0.w += __shfl_xor(a0.w, 32);
    a1.x += __shfl_xor(a1.x, 16); a1.x += __shfl_xor(a1.x, 32);
    a1.y += __shfl_xor(a1.y, 16); a1.y += __shfl_xor(a1.y, 32);
    a1.z += __shfl_xor(a1.z, 16); a1.z += __shfl_xor(a1.z, 32);
    a1.w += __shfl_xor(a1.w, 16); a1.w += __shfl_xor(a1.w, 32);
    a2.x += __shfl_xor(a2.x, 16); a2.x += __shfl_xor(a2.x, 32);
    a2.y += __shfl_xor(a2.y, 16); a2.y += __shfl_xor(a2.y, 32);
    a2.z += __shfl_xor(a2.z, 16); a2.z += __shfl_xor(a2.z, 32);
    a2.w += __shfl_xor(a2.w, 16); a2.w += __shfl_xor(a2.w, 32);
    a3.x += __shfl_xor(a3.x, 16); a3.x += __shfl_xor(a3.x, 32);
    a3.y += __shfl_xor(a3.y, 16); a3.y += __shfl_xor(a3.y, 32);
    a3.z += __shfl_xor(a3.z, 16); a3.z += __shfl_xor(a3.z, 32);
    a3.w += __shfl_xor(a3.w, 16); a3.w += __shfl_xor(a3.w, 32);
    if (sub == 0) {
        *(float4*)&ob[wid][0 * 64 + cg * 4] = a0;
        *(float4*)&ob[wid][1 * 64 + cg * 4] = a1;
        *(float4*)&ob[wid][2 * 64 + cg * 4] = a2;
        *(float4*)&ob[wid][3 * 64 + cg * 4] = a3;
    }
    __syncthreads();

    float* rec = part + ((size_t)bh * NC + c) * RECSZ;
    if (tid < 4) {
        rec[tid] = msh[tid];
        rec[4 + tid] = lsh[tid];
    }
    rec[8 + tid] = ob[0][tid] + ob[1][tid] + ob[2][tid] + ob[3][tid];
}

// ---------------------------------------------------------------------------
// Fused combine + output projection. grid (32, 16), block 256.
// Block (b, n0): rebuild batch b's combined attention activation from `part`
// (L2-resident) into LDS, then run the R2-verified GEMM against Wo.
// (Validated numerically in rounds 6 and 7.)
// ---------------------------------------------------------------------------
__global__ __launch_bounds__(256) void combine_proj_out_kernel(
    const float* __restrict__ part, const float* __restrict__ Wo,
    const float* __restrict__ bo, float* __restrict__ out) {
    __shared__ float a_lds[4 * E_];
    __shared__ float res[256];
    __shared__ float wcoef[64][NC + 1];    // [h*4+s][c], padded
    __shared__ float linv[64];
    const int b = blockIdx.x;
    const int n0 = blockIdx.y * 64;
    const int tid = threadIdx.x;

    // phase 1a: per-(h,s) combine weights
    if (tid < 64) {
        const int h = tid >> 2, s = tid & 3;
        const float* base = part + ((size_t)(b * H_ + h) * NC) * RECSZ;
        float m = -1e30f;
        #pragma unroll
        for (int c = 0; c < NC; ++c) m = fmaxf(m, base[c * RECSZ + s]);
        float l = 0.f;
        #pragma unroll
        for (int c = 0; c < NC; ++c) {
            const float w = __expf(base[c * RECSZ + s] - m);
            wcoef[tid][c] = w;
            l = fmaf(base[c * RECSZ + 4 + s], w, l);
        }
        linv[tid] = 1.f / l;
    }
    __syncthreads();

    // phase 1b: a_lds[s][h*64+dk] = sum_c w_c * O_c(s,h,dk) / l
    float4* al4 = (float4*)a_lds;
    #pragma unroll
    for (int i = 0; i < 4; ++i) {
        const int idx = tid + 256 * i;     // float4 slot: s*256 + h*16 + dkg
        const int s = idx >> 8;
        const int rest = idx & 255;
        const int h = rest >> 4, dkg = rest & 15;
        const float* base = part + ((size_t)(b * H_ + h) * NC) * RECSZ
                          + 8 + s * 64 + dkg * 4;
        float4 o = make_float4(0.f, 0.f, 0.f, 0.f);
        #pragma unroll
        for (int c = 0; c < NC; ++c) {
            const float4 v = *(const float4*)(base + c * RECSZ);
            const float w = wcoef[h * 4 + s][c];
            o.x = fmaf(w, v.x, o.x); o.y = fmaf(w, v.y, o.y);
            o.z = fmaf(w, v.z, o.z); o.w = fmaf(w, v.w, o.w);
        }
        const float li = linv[h * 4 + s];
        o.x *= li; o.y *= li; o.z *= li; o.w *= li;
        al4[idx] = o;
    }
    __syncthreads();

    gemm_block(a_lds, Wo, n0, tid, res);
    __syncthreads();

    out[(size_t)(b * 4 + (tid >> 6)) * E_ + n0 + (tid & 63)] =
        res[tid] + bo[n0 + (tid & 63)];
}

// ---------------------------------------------------------------------------
extern "C" void kernel_launch(void* const* d_in, const int* in_sizes, int n_in,
                              void* d_out, int out_size, void* d_ws, size_t ws_size,
                              hipStream_t stream) {
    const float* x  = (const float*)d_in[0];
    const float* ck = (const float*)d_in[1];
    const float* cv = (const float*)d_in[2];
    const float* Wq = (const float*)d_in[3];
    const float* bq = (const float*)d_in[4];
    const float* Wk = (const float*)d_in[5];
    const float* bk = (const float*)d_in[6];
    const float* Wv = (const float*)d_in[7];
    const float* bv = (const float*)d_in[8];
    const float* Wo = (const float*)d_in[9];
    const float* bo = (const float*)d_in[10];
    float* out = (float*)d_out;
    float* ws = (float*)d_ws;

    float* Qw = ws;                           // 131072 floats (z=0)
    float* Kn = ws + 131072;                  // 131072       (z=1)
    float* Vn = ws + 262144;                  // 131072       (z=2)
    float* part = ws + 393216;                // 512*9*264 = 1216512

    hipLaunchKernelGGL(proj_qkv_kernel, dim3(32, 16, 3), dim3(256), 0, stream,
                       x, Wq, bq, Wk, bk, Wv, bv, ws);
    hipLaunchKernelGGL(attn_partial_kernel, dim3(NBH, NC), dim3(256), 0, stream,
                       Qw, ck, cv, Kn, Vn, part);
    hipLaunchKernelGGL(combine_proj_out_kernel, dim3(32, 16), dim3(256), 0, stream,
                       part, Wo, bo, out);
}

// Round 9
// 244.920 us; speedup vs baseline: 1.6200x; 1.6047x over previous
//
#include <hip/hip_runtime.h>
#include <math.h>

#define B_   32
#define S_   4
#define H_   16
#define D_   64
#define E_   1024
#define KV_  4096
#define NBH  512            // B_*H_
#define CS   512            // cached rows per chunk
#define NC   9              // 8 cache chunks + 1 "new rows" chunk
#define RECSZ 264           // 4 m + 4 l + 256 O floats per partial record

// ---------------------------------------------------------------------------
// Small GEMM: out = A[128,1024] @ W[1024,1024]^T + bias
// Cooperative 16-lane-per-row reads: every wave load is 4x256B segments
// (16 cache lines), fully coalesced.
// mode 0: scatter to [b,h,s,d];  mode 1: linear [t][e]
// grid (32, 16), block 256
// ---------------------------------------------------------------------------
__global__ __launch_bounds__(256) void proj_kernel(
    const float* __restrict__ A, const float* __restrict__ W,
    const float* __restrict__ bias, float* __restrict__ out, int mode) {
    __shared__ float a_lds[4 * E_];
    __shared__ float res[256];
    const int t0 = blockIdx.x * 4;
    const int n0 = blockIdx.y * 64;
    const int tid = threadIdx.x;
    const int lane = tid & 63, wid = tid >> 6;
    const int sub = lane >> 4, cg = lane & 15, tsel = cg & 3;

    const float4* Ag = (const float4*)(A + (size_t)t0 * E_);
    float4* al = (float4*)a_lds;
    #pragma unroll
    for (int i = 0; i < 4; ++i) al[tid + 256 * i] = Ag[tid + 256 * i];
    __syncthreads();

    #pragma unroll
    for (int g = 0; g < 4; ++g) {
        const int r0 = n0 + wid * 16 + g * 4;       // 4 W-rows for this wave
        const float4* wrow = (const float4*)(W + (size_t)r0 * E_);
        float ac0 = 0.f, ac1 = 0.f, ac2 = 0.f, ac3 = 0.f;
        #pragma unroll
        for (int kk = 0; kk < 16; ++kk) {
            float4 w4 = wrow[sub * 256 + kk * 16 + cg];
            float4 a0 = *(const float4*)&a_lds[0 * E_ + kk * 64 + cg * 4];
            float4 a1 = *(const float4*)&a_lds[1 * E_ + kk * 64 + cg * 4];
            float4 a2 = *(const float4*)&a_lds[2 * E_ + kk * 64 + cg * 4];
            float4 a3 = *(const float4*)&a_lds[3 * E_ + kk * 64 + cg * 4];
            ac0 += w4.x * a0.x + w4.y * a0.y + w4.z * a0.z + w4.w * a0.w;
            ac1 += w4.x * a1.x + w4.y * a1.y + w4.z * a1.z + w4.w * a1.w;
            ac2 += w4.x * a2.x + w4.y * a2.y + w4.z * a2.z + w4.w * a2.w;
            ac3 += w4.x * a3.x + w4.y * a3.y + w4.z * a3.z + w4.w * a3.w;
        }
        // reduce over 16 lanes: 2 rounds on all 4, select token, 2 rounds
        ac0 += __shfl_xor(ac0, 1); ac0 += __shfl_xor(ac0, 2);
        ac1 += __shfl_xor(ac1, 1); ac1 += __shfl_xor(ac1, 2);
        ac2 += __shfl_xor(ac2, 1); ac2 += __shfl_xor(ac2, 2);
        ac3 += __shfl_xor(ac3, 1); ac3 += __shfl_xor(ac3, 2);
        float v = (tsel & 1) ? ((tsel & 2) ? ac3 : ac1)
                             : ((tsel & 2) ? ac2 : ac0);
        v += __shfl_xor(v, 4); v += __shfl_xor(v, 8);
        if (cg < 4) res[cg * 64 + (wid * 16 + g * 4 + sub)] = v;
    }
    __syncthreads();

    const float val = res[tid] + bias[n0 + (tid & 63)];
    const int t = t0 + (tid >> 6), e = n0 + (tid & 63);
    if (mode == 0) {
        const int b = t >> 2, s = t & 3, h = e >> 6, dk = e & 63;
        out[((size_t)((b * H_ + h) * S_ + s)) * D_ + dk] = val;
    } else {
        out[(size_t)t * E_ + e] = val;
    }
}

// ---------------------------------------------------------------------------
// Attention partials (flash-decoding), fully coalesced 1KB wave loads
// ---------------------------------------------------------------------------
__device__ __forceinline__ float wave_sum(float v) {
    #pragma unroll
    for (int off = 32; off > 0; off >>= 1) v += __shfl_xor(v, off);
    return v;
}

__global__ __launch_bounds__(256) void attn_partial_kernel(
    const float* __restrict__ Qw, const float* __restrict__ Kc,
    const float* __restrict__ Vc, const float* __restrict__ Kn,
    const float* __restrict__ Vn, float* __restrict__ part) {
    __shared__ float q_s[S_ * D_];
    __shared__ float ps[CS][4];
    __shared__ float ob[4][256];
    __shared__ float wred[4][4];
    __shared__ float msh[4], lsh[4];

    const int bh = blockIdx.x;
    const int c = blockIdx.y;
    const int tid = threadIdx.x;
    const int lane = tid & 63, wid = tid >> 6;
    const int sub = lane >> 4, cg = lane & 15, qsel = cg & 3;

    q_s[tid] = Qw[(size_t)bh * 256 + tid];
    __syncthreads();

    const float* kptr;
    const float* vptr;
    int nrows;
    if (c < 8) {
        kptr = Kc + ((size_t)bh * KV_ + c * CS) * D_;
        vptr = Vc + ((size_t)bh * KV_ + c * CS) * D_;
        nrows = CS;
    } else {
        kptr = Kn + (size_t)bh * 256;
        vptr = Vn + (size_t)bh * 256;
        nrows = S_;
    }

    // per-lane Q fragments: query q, dims cg*4 .. cg*4+3
    const float4 q0 = *(const float4*)&q_s[0 * 64 + cg * 4];
    const float4 q1 = *(const float4*)&q_s[1 * 64 + cg * 4];
    const float4 q2 = *(const float4*)&q_s[2 * 64 + cg * 4];
    const float4 q3 = *(const float4*)&q_s[3 * 64 + cg * 4];

    // ---- score phase: wave load = 4 consecutive K rows (1KB contiguous) ----
    float mrun = -1e30f;
    for (int r0 = wid * 4; r0 < nrows; r0 += 16) {
        float4 kv = ((const float4*)(kptr + (size_t)r0 * D_))[lane];
        float p0 = kv.x * q0.x + kv.y * q0.y + kv.z * q0.z + kv.w * q0.w;
        float p1 = kv.x * q1.x + kv.y * q1.y + kv.z * q1.z + kv.w * q1.w;
        float p2 = kv.x * q2.x + kv.y * q2.y + kv.z * q2.z + kv.w * q2.w;
        float p3 = kv.x * q3.x + kv.y * q3.y + kv.z * q3.z + kv.w * q3.w;
        p0 += __shfl_xor(p0, 1); p0 += __shfl_xor(p0, 2);
        p1 += __shfl_xor(p1, 1); p1 += __shfl_xor(p1, 2);
        p2 += __shfl_xor(p2, 1); p2 += __shfl_xor(p2, 2);
        p3 += __shfl_xor(p3, 1); p3 += __shfl_xor(p3, 2);
        float v = (qsel & 1) ? ((qsel & 2) ? p3 : p1)
                             : ((qsel & 2) ? p2 : p0);
        v += __shfl_xor(v, 4); v += __shfl_xor(v, 8);
        v *= 0.125f;                                 // 1/sqrt(64)
        mrun = fmaxf(mrun, v);
        if (cg < 4) ps[r0 + sub][cg] = v;
    }
    // wave max over its rows (sub dimension), then block max
    mrun = fmaxf(mrun, __shfl_xor(mrun, 16));
    mrun = fmaxf(mrun, __shfl_xor(mrun, 32));
    if (lane < 4) wred[lane][wid] = mrun;
    __syncthreads();
    if (tid < 4) {
        msh[tid] = fmaxf(fmaxf(wred[tid][0], wred[tid][1]),
                         fmaxf(wred[tid][2], wred[tid][3]));
    }
    __syncthreads();
    const float m0 = msh[0], m1 = msh[1], m2 = msh[2], m3 = msh[3];

    // ---- exp pass: ps -> exp(ps - m), accumulate l ----
    float4 tl = make_float4(0.f, 0.f, 0.f, 0.f);
    for (int r = tid; r < nrows; r += 256) {
        float4 s = *(float4*)ps[r];
        s.x = __expf(s.x - m0); s.y = __expf(s.y - m1);
        s.z = __expf(s.z - m2); s.w = __expf(s.w - m3);
        *(float4*)ps[r] = s;
        tl.x += s.x; tl.y += s.y; tl.z += s.z; tl.w += s.w;
    }
    tl.x = wave_sum(tl.x); tl.y = wave_sum(tl.y);
    tl.z = wave_sum(tl.z); tl.w = wave_sum(tl.w);
    if (lane == 0) {
        wred[0][wid] = tl.x; wred[1][wid] = tl.y;
        wred[2][wid] = tl.z; wred[3][wid] = tl.w;
    }
    __syncthreads();
    if (tid < 4) {
        lsh[tid] = wred[tid][0] + wred[tid][1] + wred[tid][2] + wred[tid][3];
    }
    __syncthreads();   // ps[] fully exp'd and visible

    // ---- phase B: wave load = 4 consecutive V rows (1KB contiguous) ----
    float4 a0 = make_float4(0.f, 0.f, 0.f, 0.f);
    float4 a1 = a0, a2 = a0, a3 = a0;
    for (int r0 = wid * 4; r0 < nrows; r0 += 16) {
        float4 vv = ((const float4*)(vptr + (size_t)r0 * D_))[lane];
        float4 p = *(const float4*)ps[r0 + sub];     // this lane's row weights
        a0.x = fmaf(p.x, vv.x, a0.x); a0.y = fmaf(p.x, vv.y, a0.y);
        a0.z = fmaf(p.x, vv.z, a0.z); a0.w = fmaf(p.x, vv.w, a0.w);
        a1.x = fmaf(p.y, vv.x, a1.x); a1.y = fmaf(p.y, vv.y, a1.y);
        a1.z = fmaf(p.y, vv.z, a1.z); a1.w = fmaf(p.y, vv.w, a1.w);
        a2.x = fmaf(p.z, vv.x, a2.x); a2.y = fmaf(p.z, vv.y, a2.y);
        a2.z = fmaf(p.z, vv.z, a2.z); a2.w = fmaf(p.z, vv.w, a2.w);
        a3.x = fmaf(p.w, vv.x, a3.x); a3.y = fmaf(p.w, vv.y, a3.y);
        a3.z = fmaf(p.w, vv.z, a3.z); a3.w = fmaf(p.w, vv.w, a3.w);
    }
    // sum the 4 sub-groups (same dims, different rows)
    a0.x += __shfl_xor(a0.x, 16); a0.x += __shfl_xor(a0.x, 32);
    a0.y += __shfl_xor(a0.y, 16); a0.y += __shfl_xor(a0.y, 32);
    a0.z += __shfl_xor(a0.z, 16); a0.z += __shfl_xor(a0.z, 32);
    a0.w += __shfl_xor(a0.w, 16); a0.w += __shfl_xor(a0.w, 32);
    a1.x += __shfl_xor(a1.x, 16); a1.x += __shfl_xor(a1.x, 32);
    a1.y += __shfl_xor(a1.y, 16); a1.y += __shfl_xor(a1.y, 32);
    a1.z += __shfl_xor(a1.z, 16); a1.z += __shfl_xor(a1.z, 32);
    a1.w += __shfl_xor(a1.w, 16); a1.w += __shfl_xor(a1.w, 32);
    a2.x += __shfl_xor(a2.x, 16); a2.x += __shfl_xor(a2.x, 32);
    a2.y += __shfl_xor(a2.y, 16); a2.y += __shfl_xor(a2.y, 32);
    a2.z += __shfl_xor(a2.z, 16); a2.z += __shfl_xor(a2.z, 32);
    a2.w += __shfl_xor(a2.w, 16); a2.w += __shfl_xor(a2.w, 32);
    a3.x += __shfl_xor(a3.x, 16); a3.x += __shfl_xor(a3.x, 32);
    a3.y += __shfl_xor(a3.y, 16); a3.y += __shfl_xor(a3.y, 32);
    a3.z += __shfl_xor(a3.z, 16); a3.z += __shfl_xor(a3.z, 32);
    a3.w += __shfl_xor(a3.w, 16); a3.w += __shfl_xor(a3.w, 32);
    if (sub == 0) {
        *(float4*)&ob[wid][0 * 64 + cg * 4] = a0;
        *(float4*)&ob[wid][1 * 64 + cg * 4] = a1;
        *(float4*)&ob[wid][2 * 64 + cg * 4] = a2;
        *(float4*)&ob[wid][3 * 64 + cg * 4] = a3;
    }
    __syncthreads();

    float* rec = part + ((size_t)bh * NC + c) * RECSZ;
    if (tid < 4) {
        rec[tid] = msh[tid];
        rec[4 + tid] = lsh[tid];
    }
    rec[8 + tid] = ob[0][tid] + ob[1][tid] + ob[2][tid] + ob[3][tid];
}

// ---------------------------------------------------------------------------
// Combine partials: attn output in [B,S,E] layout
// ---------------------------------------------------------------------------
__global__ __launch_bounds__(256) void attn_combine_kernel(
    const float* __restrict__ part, float* __restrict__ attn_out) {
    const int bh = blockIdx.x;
    const int tid = threadIdx.x;
    const int q = tid >> 6, dl = tid & 63;
    const float* base = part + (size_t)bh * NC * RECSZ;

    float m = -1e30f;
    #pragma unroll
    for (int c = 0; c < NC; ++c) m = fmaxf(m, base[c * RECSZ + q]);
    float l = 0.f, o = 0.f;
    #pragma unroll
    for (int c = 0; c < NC; ++c) {
        float w = __expf(base[c * RECSZ + q] - m);
        l = fmaf(base[c * RECSZ + 4 + q], w, l);
        o = fmaf(base[c * RECSZ + 8 + tid], w, o);
    }
    const float res = o / l;
    const int b = bh >> 4, h = bh & 15;
    attn_out[((size_t)(b * S_ + q)) * E_ + h * D_ + dl] = res;
}

// ---------------------------------------------------------------------------
extern "C" void kernel_launch(void* const* d_in, const int* in_sizes, int n_in,
                              void* d_out, int out_size, void* d_ws, size_t ws_size,
                              hipStream_t stream) {
    const float* x  = (const float*)d_in[0];
    const float* ck = (const float*)d_in[1];
    const float* cv = (const float*)d_in[2];
    const float* Wq = (const float*)d_in[3];
    const float* bq = (const float*)d_in[4];
    const float* Wk = (const float*)d_in[5];
    const float* bk = (const float*)d_in[6];
    const float* Wv = (const float*)d_in[7];
    const float* bv = (const float*)d_in[8];
    const float* Wo = (const float*)d_in[9];
    const float* bo = (const float*)d_in[10];
    float* out = (float*)d_out;
    float* ws = (float*)d_ws;

    float* Qw = ws;                       // 131072 floats
    float* Kn = ws + 131072;              // 131072
    float* Vn = ws + 262144;              // 131072
    float* part = ws + 393216;            // 512*9*264 = 1216512
    float* attn_out = ws + 393216 + 1216512;  // 131072

    dim3 pg(32, 16), pb(256);
    hipLaunchKernelGGL(proj_kernel, pg, pb, 0, stream, x, Wq, bq, Qw, 0);
    hipLaunchKernelGGL(proj_kernel, pg, pb, 0, stream, x, Wk, bk, Kn, 0);
    hipLaunchKernelGGL(proj_kernel, pg, pb, 0, stream, x, Wv, bv, Vn, 0);
    hipLaunchKernelGGL(attn_partial_kernel, dim3(NBH, NC), dim3(256), 0, stream,
                       Qw, ck, cv, Kn, Vn, part);
    hipLaunchKernelGGL(attn_combine_kernel, dim3(NBH), dim3(256), 0, stream,
                       part, attn_out);
    hipLaunchKernelGGL(proj_kernel, pg, pb, 0, stream, attn_out, Wo, bo, out, 1);
}